// Round 1
// baseline (255.022 us; speedup 1.0000x reference)
//
#include <hip/hip_runtime.h>
#include <math.h>

// SPU transformer: pure elementwise over N rows of (l,u) with 3 more (N,2)
// inputs. Memory-bound: 32 B read + 8 B write per row -> roofline ~53 us at
// 6.3 TB/s. Each thread processes 2 rows via float4 (16 B/lane coalesced).

__device__ __forceinline__ float spu_f(float x) {
    // x >= 0: x*x - 0.5 ; x < 0: sigmoid(-x) - 1 = 1/(1+e^x) - 1
    if (x >= 0.0f) {
        return x * x - 0.5f;
    } else {
        return 1.0f / (1.0f + __expf(x)) - 1.0f;
    }
}

__device__ __forceinline__ void spu_row(float l, float u,
                                        float p1l, float p1u,
                                        float q1l, float q1u,
                                        float b0l, float b0u,
                                        float& out_lo, float& out_hi) {
    const float sl = spu_f(l);
    const float su = spu_f(u);

    const bool neg   = (u <= 0.0f);
    const bool pos   = (l >= 0.0f);
    const bool cross = !(neg || pos);

    const float all_slopes = (su - sl) / (u - l);

    const float s0 = neg ? all_slopes : 0.0f;
    const float s1 = (pos || cross) ? all_slopes : 0.0f;

    const bool neg_slope = (all_slopes < 0.0f);
    float lo = neg_slope ? su : sl;
    float hi = neg_slope ? sl : su;
    lo = cross ? -0.5f : lo;

    float sh1 = fmaf(-s1, u, su);  // su - s1*u
    float sh0 = fmaf(-s0, l, sl);  // sl - s0*l
    sh0 = cross ? -0.5f : sh0;
    sh1 = neg ? sl : sh1;

    const float s1p = fmaxf(s1, 0.0f), s1n = fminf(s1, 0.0f);
    const float s0p = fmaxf(s0, 0.0f), s0n = fminf(s0, 0.0f);

    const float UBM = s1p * p1u + s1n * p1l;
    const float UBV = s1p * q1u + sh1 + s1n * q1l;
    const float LBM = s0p * p1l + s0n * p1u;
    const float LBV = s0n * q1l + sh0 + s0p * q1u;

    const float lower = fmaxf(LBM, 0.0f) * b0l + fminf(LBM, 0.0f) * b0u + LBV;
    const float upper = fmaxf(UBM, 0.0f) * b0u + fminf(UBM, 0.0f) * b0l + UBV;

    out_lo = (lower > lo) ? lower : lo;
    out_hi = (upper < hi) ? upper : hi;
}

__global__ __launch_bounds__(256) void SPUTransformer_62002147885333_kernel(
    const float4* __restrict__ bounds,
    const float4* __restrict__ slopes_prev,
    const float4* __restrict__ shifts_prev,
    const float4* __restrict__ bounds_prev,
    float4* __restrict__ out,
    int npairs)  // npairs = N/2; one float4 = two (l,u) rows
{
    const int stride = gridDim.x * blockDim.x;
    for (int i = blockIdx.x * blockDim.x + threadIdx.x; i < npairs; i += stride) {
        const float4 b  = bounds[i];
        const float4 sp = slopes_prev[i];
        const float4 sh = shifts_prev[i];
        const float4 bp = bounds_prev[i];
        float4 o;
        spu_row(b.x, b.y, sp.x, sp.y, sh.x, sh.y, bp.x, bp.y, o.x, o.y);
        spu_row(b.z, b.w, sp.z, sp.w, sh.z, sh.w, bp.z, bp.w, o.z, o.w);
        out[i] = o;
    }
}

extern "C" void kernel_launch(void* const* d_in, const int* in_sizes, int n_in,
                              void* d_out, int out_size, void* d_ws, size_t ws_size,
                              hipStream_t stream) {
    // Inputs (setup_inputs order): bounds (N,2), slopes_prev (N,2),
    // shifts_prev (N,2), bounds_prev (N,2) -- all float32.
    const float4* bounds      = (const float4*)d_in[0];
    const float4* slopes_prev = (const float4*)d_in[1];
    const float4* shifts_prev = (const float4*)d_in[2];
    const float4* bounds_prev = (const float4*)d_in[3];
    float4* out = (float4*)d_out;

    const int n_rows = in_sizes[0] / 2;   // N
    const int npairs = n_rows / 2;        // N even (8388608)

    const int block = 256;
    int grid = (npairs + block - 1) / block;
    if (grid > 65535 * 8) grid = 65535 * 8;  // grid-stride handles remainder

    SPUTransformer_62002147885333_kernel<<<grid, block, 0, stream>>>(
        bounds, slopes_prev, shifts_prev, bounds_prev, out, npairs);
}